// Round 4
// baseline (236.156 us; speedup 1.0000x reference)
//
#include <hip/hip_runtime.h>
#include <hip/hip_bf16.h>
#include <hip/hip_fp16.h>
#include <cstdint>

// ---------- types ----------
typedef unsigned short us;
typedef us   us8 __attribute__((ext_vector_type(8)));
typedef short s8v __attribute__((ext_vector_type(8)));   // 8 bf16 (4 VGPRs) MFMA A/B frag
typedef float f4v __attribute__((ext_vector_type(4)));   // MFMA C/D frag
typedef __fp16 pk2 __attribute__((ext_vector_type(2))); // cvt_pkrtz result type

// Problem constants (B=4, S=4096, D=1024 fixed by setup_inputs)
#define BB 4
#define SS 4096
#define DD 1024
#define MM (BB * SS)      // 16384
#define NN (2 * DD)       // 2048
#define KK DD             // 1024

// GEMM tiling (R3/R4: 256x256 8-phase schedule, 8 waves)
#define BM 256
#define BN 256            // W rows = 128 channels
#define BK 64

// Scan chunking: 32-step chunks; one 256-row GEMM tile = exactly 8 chunks
#define CHUNK 32
#define NC (SS / CHUNK)   // 128
#define BDD (BB * DD)     // 4096 sequences
#define DQ (DD / 4)       // 256 channel-quads (pass3 vectorization)

// ---------- fp32 -> bf16 (RNE) ----------
__device__ inline us f2bf(float f) {
  unsigned u = __float_as_uint(f);
  u += 0x7fffu + ((u >> 16) & 1u);
  return (us)(u >> 16);
}

// one launch converts both x and W (x occupies blocks [0, 8192), W the rest)
__global__ __launch_bounds__(256) void cvt_both(const float* __restrict__ x,
                                                const float* __restrict__ W,
                                                us* __restrict__ xb,
                                                us* __restrict__ wb,
                                                long nx) {
  long i = ((long)blockIdx.x * 256 + threadIdx.x) * 8;
  const float* in;
  us* out;
  if (i < nx) { in = x + i; out = xb + i; }
  else        { in = W + (i - nx); out = wb + (i - nx); }
  const float4* p = (const float4*)in;
  float4 a = p[0], b = p[1];
  us8 o;
  o[0] = f2bf(a.x); o[1] = f2bf(a.y); o[2] = f2bf(a.z); o[3] = f2bf(a.w);
  o[4] = f2bf(b.x); o[5] = f2bf(b.y); o[6] = f2bf(b.z); o[7] = f2bf(b.w);
  *(us8*)out = o;
}

// ---------- async global->LDS, 16B per lane ----------
#define GLD16(g, l)                                                        \
  __builtin_amdgcn_global_load_lds(                                        \
      (const __attribute__((address_space(1))) void*)(g),                  \
      (__attribute__((address_space(3))) void*)(l), 16, 0, 0)

// ---------- gate math ----------
// h_t = coef*h_{t-1} + v ;  coef = sigmoid(-gate), v = sigmoid(gate)*g(hidden)
// g(x) = x+0.5 (x>=0) else sigmoid(x). Fast: v_exp + v_rcp (1 ulp), no divides.
__device__ inline void gate_cv(float hid, float gat, float& coef, float& v) {
  float e = __expf(gat);
  coef = __builtin_amdgcn_rcpf(1.0f + e);      // sigmoid(-gate)
  float z = 1.0f - coef;                        // sigmoid(gate), robust at e=inf
  float eh = __expf(hid < 0.0f ? hid : 0.0f);   // only meaningful on neg path
  float gneg = eh * __builtin_amdgcn_rcpf(1.0f + eh);  // eh<=1: safe
  float g = (hid >= 0.0f) ? (hid + 0.5f) : gneg;
  v = z * g;
}

// ---------- fused GEMM + gate epilogue + chunk-local scan (pass1) ----------
// 256x256 tile, 8 waves (2Mx4N), BK=64, double-buffered LDS (128 KiB),
// 8-phase counted-vmcnt schedule (T3+T4 per cdna4 guide §5) + setprio (T5).
// Staging ledger (iter i: compute t0=2i in buf0 [p0-3], t1=2i+1 in buf1
// [p4-7]; stage s0=2i+2 -> buf0, s1=2i+3 -> buf1):
//   p0: A(t1) rows {64-127,192-255}   (region freed by p6-7 of prev iter)
//   p1: B(s0) rows 0-127              (all B(t0) frags read at p0)
//   p2: B(s0) rows 128-255
//   p3: A(s0) rows {0-63,128-191} + vmcnt(6)   (A(t0) q0-1 read p0-1)
//   p4: A(s0) rows {64-127,192-255}            (A(t0) q2-3 read p2-3)
//   p5: B(s1) rows 0-127              (B(t1) frags read at p4)
//   p6: B(s1) rows 128-255
//   p7: A(s1) rows {0-63,128-191} + vmcnt(6)
// FIFO proof: at p3 (14 outstanding) vmcnt(6) lands {B(t1)x4, A(t1)x4} =
// everything p4-p7 reads; at p7 it lands all of s0 = everything next-iter
// p0-p3 reads. Barrier after each vmcnt broadcasts the per-wave proof.
// Tail (i=7): stage tiles clamp to 14/15 = rewrite identical bytes
// (race-safe by value); vmcnt(0)+barrier before the LDS->T epilogue reuse.
// Epilogue identical math to the 128^2 version (bit-identical acc: same
// MFMA shape and K order), T is now [256 rows][128 ch] = full 128 KiB LDS.
__global__ __launch_bounds__(512, 2) void gemm_fused(const us* __restrict__ A,
                                                     const us* __restrict__ Bw,
                                                     unsigned* __restrict__ cv,
                                                     float* __restrict__ cp,
                                                     float* __restrict__ ch) {
  __shared__ __align__(16) us smem[4 * 256 * 64];   // 128 KiB
  us* As0 = smem;
  us* Bs0 = smem + 256 * 64;
  us* As1 = smem + 2 * 256 * 64;
  us* Bs1 = smem + 3 * 256 * 64;
  unsigned* T = (unsigned*)smem;                     // epilogue: [256][128]

  const int tid  = threadIdx.x;
  const int lane = tid & 63;
  const int w    = tid >> 6;      // wave 0..7
  const int wm   = w & 1;         // 2x4 wave grid
  const int wn   = w >> 1;        // 0..3
  const long bm  = (long)blockIdx.x * BM;
  const int  d0  = blockIdx.y * 128;   // global channel base

  // staging geometry: one global_load_lds per wave = 8 rows x 64 cols (1 KiB)
  const int srow = lane >> 3;                 // row within 8-row group
  const int sseg = (lane & 7) ^ srow;         // XOR-permuted source segment

  const int fr = lane & 15;
  const int fq = lane >> 4;                   // 0..3
  const int f7 = fr & 7;

  // per-wave stage row bases
  const int a_r0 = ((w >> 2) * 128) + ((w & 3) * 16);  // A: waves 0-3 half0, 4-7 half1
  const int b_r0 = w * 16;                             // B: 8 waves x 16 rows

  const us* Abase = A + (bm + srow) * (long)KK + sseg * 8;

  auto stA = [&](int r0, int kt, us* dst) {
    GLD16(Abase + (long)r0 * KK + kt * 64, dst + r0 * 64);
  };
  auto stB = [&](int r0, int kt, us* dst) {
    int lr = r0 + srow;
    int wrow = d0 + ((lr >> 5) << 4) + (lr & 15) + (((lr >> 4) & 1) << 10);
    GLD16(Bw + (long)wrow * KK + kt * 64 + sseg * 8, dst + r0 * 64);
  };

  f4v acc[8][4] = {};

  // ---- prologue: tile0 A+B (8 loads first), tile1 B, tile1 A h1 ----
  stA(a_r0, 0, As0);       stA(a_r0 + 8, 0, As0);
  stA(a_r0 + 64, 0, As0);  stA(a_r0 + 72, 0, As0);
  stB(b_r0, 0, Bs0);       stB(b_r0 + 8, 0, Bs0);
  stB(b_r0 + 128, 0, Bs0); stB(b_r0 + 136, 0, Bs0);
  stB(b_r0, 1, Bs1);       stB(b_r0 + 8, 1, Bs1);
  stB(b_r0 + 128, 1, Bs1); stB(b_r0 + 136, 1, Bs1);
  stA(a_r0, 1, As1);       stA(a_r0 + 8, 1, As1);
  asm volatile("s_waitcnt vmcnt(6)" ::: "memory");   // tile0 fully landed
  __builtin_amdgcn_s_barrier();

  s8v bf[4][2];   // B frags held across the 4 phases of a K-tile
  for (int it = 0; it < 8; ++it) {
    const int t1 = 2 * it + 1;
    const int s0 = (it < 7) ? (2 * it + 2) : 14;   // tail: identical-byte restage
    const int s1 = (it < 7) ? (2 * it + 3) : 15;
#pragma unroll
    for (int p = 0; p < 8; ++p) {
      const int q = p & 3;                         // quadrant (mt pair)
      const us* Asb = (p < 4) ? As0 : As1;
      const us* Bsb = (p < 4) ? Bs0 : Bs1;
      // ---- ds-load register subtile ----
      if (q == 0) {
#pragma unroll
        for (int nt = 0; nt < 4; ++nt)
#pragma unroll
          for (int kk = 0; kk < 2; ++kk)
            bf[nt][kk] = *(const s8v*)&Bsb[(wn * 64 + nt * 16 + fr) * 64 +
                                           (((kk * 4 + fq) ^ f7) * 8)];
      }
      s8v af[2][2];
#pragma unroll
      for (int m2 = 0; m2 < 2; ++m2)
#pragma unroll
        for (int kk = 0; kk < 2; ++kk)
          af[m2][kk] = *(const s8v*)&Asb[(wm * 128 + (2 * q + m2) * 16 + fr) * 64 +
                                         (((kk * 4 + fq) ^ f7) * 8)];
      // ---- stage one half-tile (2 loads/wave) per ledger ----
      if (p == 0)      { stA(a_r0 + 64, t1, As1); stA(a_r0 + 72, t1, As1); }
      else if (p == 1) { stB(b_r0, s0, Bs0);       stB(b_r0 + 8, s0, Bs0); }
      else if (p == 2) { stB(b_r0 + 128, s0, Bs0); stB(b_r0 + 136, s0, Bs0); }
      else if (p == 3) { stA(a_r0, s0, As0);       stA(a_r0 + 8, s0, As0);
                         asm volatile("s_waitcnt vmcnt(6)" ::: "memory"); }
      else if (p == 4) { stA(a_r0 + 64, s0, As0);  stA(a_r0 + 72, s0, As0); }
      else if (p == 5) { stB(b_r0, s1, Bs1);       stB(b_r0 + 8, s1, Bs1); }
      else if (p == 6) { stB(b_r0 + 128, s1, Bs1); stB(b_r0 + 136, s1, Bs1); }
      else             { stA(a_r0, s1, As1);       stA(a_r0 + 8, s1, As1);
                         asm volatile("s_waitcnt vmcnt(6)" ::: "memory"); }
      __builtin_amdgcn_s_barrier();
      asm volatile("s_waitcnt lgkmcnt(0)" ::: "memory");
      __builtin_amdgcn_s_setprio(1);
#pragma unroll
      for (int kk = 0; kk < 2; ++kk)
#pragma unroll
        for (int m2 = 0; m2 < 2; ++m2)
#pragma unroll
          for (int nt = 0; nt < 4; ++nt)
            acc[2 * q + m2][nt] = __builtin_amdgcn_mfma_f32_16x16x32_bf16(
                af[m2][kk], bf[nt][kk], acc[2 * q + m2][nt], 0, 0, 0);
      __builtin_amdgcn_s_setprio(0);
      __builtin_amdgcn_s_barrier();
    }
  }

  // ---- epilogue ----
  asm volatile("s_waitcnt vmcnt(0)" ::: "memory");   // drain tail restages
  __builtin_amdgcn_s_barrier();                      // LDS now reusable as T
  // C/D row = fq*4 + r, col = fr (m89 layout); hid/gate pair = (nt=2p, 2p+1)
#pragma unroll
  for (int mt = 0; mt < 8; ++mt) {
    int lr0 = wm * 128 + mt * 16 + fq * 4;    // local row base
#pragma unroll
    for (int pp = 0; pp < 2; ++pp) {
      int ld = (wn * 2 + pp) * 16 + fr;       // local channel 0..127
      f4v hv = acc[mt][2 * pp];
      f4v gv = acc[mt][2 * pp + 1];
#pragma unroll
      for (int r = 0; r < 4; ++r) {
        float coef, v;
        gate_cv(hv[r], gv[r], coef, v);
        pk2 pk = __builtin_amdgcn_cvt_pkrtz(coef, v);   // (lo=coef, hi=v)
        T[(lr0 + r) * 128 + ld] = __builtin_bit_cast(unsigned, pk);
      }
    }
  }
  __syncthreads();   // transpose complete (full drain semantics)

  // (1) coalesced cv writes: 8192 uint4 chunks (256 rows x 32), 16 per thread
#pragma unroll
  for (int j = 0; j < 16; ++j) {
    int chunk = j * 512 + tid;
    int row = chunk >> 5;                     // 0..255
    int qq  = chunk & 31;                     // 16B chunk within row
    uint4 val = *(const uint4*)&T[row * 128 + qq * 4];
    *(uint4*)(cv + (size_t)(bm + row) * DD + d0 + qq * 4) = val;
  }

  // (2) chunk-local scan: 8 chunks x 128 ch = 1024 tasks, 2 per thread
  {
    const int d  = tid & 127;
    const int c0 = tid >> 7;                  // 0..3
    const int b  = (int)(bm / SS);
    const int cg0 = (int)((bm % SS) / CHUNK); // global chunk base (mult of 8)
#pragma unroll
    for (int half = 0; half < 2; ++half) {
      const int c = c0 + half * 4;            // local chunk 0..7
      float P = 1.0f, h = 0.0f;
#pragma unroll
      for (int i2 = 0; i2 < CHUNK; ++i2) {
        unsigned u = T[(c * CHUNK + i2) * 128 + d];
        __half2 hv2 = *(__half2*)&u;
        float cf = __half2float(hv2.x);
        h = fmaf(cf, h, __half2float(hv2.y));
        P *= cf;
      }
      const int idx = (cg0 + c) * BDD + b * DD + d0 + d;   // [chunk][b][d]
      cp[idx] = P;
      ch[idx] = h;
    }
  }
}

// pass2: serial scan over NC chunk summaries per sequence; 4096 threads.
// (R1 version, measured-best: 16-deep load batching for ILP; the R2
// lookback fusion regressed +7us and was reverted.)
__global__ __launch_bounds__(256) void scan_pass2(const float* __restrict__ cp,
                                                  const float* __restrict__ ch,
                                                  float* __restrict__ carry) {
  const int bd = blockIdx.x * 256 + threadIdx.x;  // 0..4095
  float h = 0.0f;
  for (int cb = 0; cb < NC; cb += 16) {
    float p[16], v[16];
#pragma unroll
    for (int i = 0; i < 16; ++i) {
      p[i] = cp[(cb + i) * BDD + bd];
      v[i] = ch[(cb + i) * BDD + bd];
    }
#pragma unroll
    for (int i = 0; i < 16; ++i) {
      carry[(cb + i) * BDD + bd] = h;               // carry INTO chunk cb+i
      h = fmaf(p[i], h, v[i]);
    }
  }
}

// pass3: re-run each chunk with the correct carry-in, write out (R1 version:
// 16B/lane uint4 cv read, float4 out write; 4 channels/thread).
__global__ __launch_bounds__(256) void scan_pass3(const uint4* __restrict__ cv,
                                                  const float* __restrict__ carry,
                                                  float4* __restrict__ out) {
  const int q = threadIdx.x;                      // 0..255 channel-quad
  const int c = blockIdx.y;
  const int b = blockIdx.z;
  const size_t rbase = ((size_t)b * SS + (size_t)c * CHUNK) * DQ + q;
  const uint4* base = cv + rbase;
  float4* obase = out + rbase;
  float4 h = *(const float4*)&carry[c * BDD + b * DD + 4 * q];
#pragma unroll 4
  for (int t = 0; t < CHUNK; ++t) {
    uint4 u = base[(size_t)t * DQ];
    __half2 a0 = *(__half2*)&u.x;
    __half2 a1 = *(__half2*)&u.y;
    __half2 a2 = *(__half2*)&u.z;
    __half2 a3 = *(__half2*)&u.w;
    h.x = fmaf(__half2float(a0.x), h.x, __half2float(a0.y));
    h.y = fmaf(__half2float(a1.x), h.y, __half2float(a1.y));
    h.z = fmaf(__half2float(a2.x), h.z, __half2float(a2.y));
    h.w = fmaf(__half2float(a3.x), h.w, __half2float(a3.y));
    obase[(size_t)t * DQ] = h;
  }
}

// ---------- launch ----------
extern "C" void kernel_launch(void* const* d_in, const int* in_sizes, int n_in,
                              void* d_out, int out_size, void* d_ws, size_t ws_size,
                              hipStream_t stream) {
  const float* x = (const float*)d_in[0];   // [4,4096,1024] fp32
  const float* W = (const float*)d_in[1];   // [2048,1024]  fp32
  float4* out = (float4*)d_out;             // [4,4096,1024] fp32

  const long nx = (long)MM * KK;            // 16,777,216
  const long nw = (long)NN * KK;            //  2,097,152

  // workspace layout (~106 MiB total)
  char* ws = (char*)d_ws;
  unsigned* cv = (unsigned*)ws;      ws += (size_t)MM * DD * sizeof(unsigned); // 64 MiB
  us* xb = (us*)ws;                  ws += (size_t)nx * sizeof(us);            // 32 MiB
  us* wb = (us*)ws;                  ws += (size_t)nw * sizeof(us);            //  4 MiB
  float* cp = (float*)ws;            ws += (size_t)NC * BDD * sizeof(float);   //  2 MiB
  float* chh = (float*)ws;           ws += (size_t)NC * BDD * sizeof(float);   //  2 MiB
  float* carry = (float*)ws;         ws += (size_t)NC * BDD * sizeof(float);   //  2 MiB

  cvt_both<<<(int)((nx + nw) / 8 / 256), 256, 0, stream>>>(x, W, xb, wb, nx);

  gemm_fused<<<dim3(MM / BM, NN / BN), 512, 0, stream>>>(xb, wb, cv, cp, chh);

  scan_pass2<<<dim3(BDD / 256), 256, 0, stream>>>(cp, chh, carry);
  scan_pass3<<<dim3(1, NC, BB), 256, 0, stream>>>((const uint4*)cv, carry, out);
}

// Round 5
// 226.869 us; speedup vs baseline: 1.0409x; 1.0409x over previous
//
#include <hip/hip_runtime.h>
#include <hip/hip_bf16.h>
#include <hip/hip_fp16.h>
#include <cstdint>

// ---------- types ----------
typedef unsigned short us;
typedef us   us4 __attribute__((ext_vector_type(4)));
typedef short s8v __attribute__((ext_vector_type(8)));   // 8 bf16 (4 VGPRs) MFMA A/B frag
typedef float f4v __attribute__((ext_vector_type(4)));   // MFMA C/D frag
typedef __fp16 pk2 __attribute__((ext_vector_type(2))); // cvt_pkrtz result type

// Problem constants (B=4, S=4096, D=1024 fixed by setup_inputs)
#define BB 4
#define SS 4096
#define DD 1024
#define MM (BB * SS)      // 16384
#define NN (2 * DD)       // 2048
#define KK DD             // 1024

// GEMM tiling (R5: reverted to the measured-best 128^2 2-phase structure;
// the 256^2 8-phase port REGRESSED 93->100us, MfmaUtil 32->27.7% — the
// counted-vmcnt schedule did not transfer to this K=1024 fused-epilogue
// shape. Both structures sit at the ~33us MFMA floor + schedule overhead.)
#define BM 128
#define BN 128
#define BK 64

// Scan chunking: 32-step chunks; one 128-row GEMM tile = exactly 4 chunks
#define CHUNK 32
#define NC (SS / CHUNK)   // 128
#define BDD (BB * DD)     // 4096 sequences
#define DQ (DD / 4)       // 256 channel-quads (pass3 vectorization)

// ---------- fp32 -> bf16 (RNE) ----------
__device__ inline us f2bf(float f) {
  unsigned u = __float_as_uint(f);
  u += 0x7fffu + ((u >> 16) & 1u);
  return (us)(u >> 16);
}

// one launch converts both x and W (x occupies the first nx/4 quads).
// R5: one float4 per thread (16B lane-contiguous loads, 8B stores) — the
// old 2x-float4-at-32B-stride layout made each load instruction a strided
// 50%-per-line pattern. Same per-element RNE -> bit-identical output.
__global__ __launch_bounds__(256) void cvt_both(const float* __restrict__ x,
                                                const float* __restrict__ W,
                                                us* __restrict__ xb,
                                                us* __restrict__ wb,
                                                long nx) {
  long i = ((long)blockIdx.x * 256 + threadIdx.x) * 4;
  const float* in;
  us* out;
  if (i < nx) { in = x + i; out = xb + i; }
  else        { in = W + (i - nx); out = wb + (i - nx); }
  float4 a = *(const float4*)in;
  us4 o;
  o[0] = f2bf(a.x); o[1] = f2bf(a.y); o[2] = f2bf(a.z); o[3] = f2bf(a.w);
  *(us4*)out = o;
}

// ---------- async global->LDS, 16B per lane ----------
#define GLD16(g, l)                                                        \
  __builtin_amdgcn_global_load_lds(                                        \
      (const __attribute__((address_space(1))) void*)(g),                  \
      (__attribute__((address_space(3))) void*)(l), 16, 0, 0)

// ---------- gate math ----------
// h_t = coef*h_{t-1} + v ;  coef = sigmoid(-gate), v = sigmoid(gate)*g(hidden)
// g(x) = x+0.5 (x>=0) else sigmoid(x). Fast: v_exp + v_rcp (1 ulp), no divides.
__device__ inline void gate_cv(float hid, float gat, float& coef, float& v) {
  float e = __expf(gat);
  coef = __builtin_amdgcn_rcpf(1.0f + e);      // sigmoid(-gate)
  float z = 1.0f - coef;                        // sigmoid(gate), robust at e=inf
  float eh = __expf(hid < 0.0f ? hid : 0.0f);   // only meaningful on neg path
  float gneg = eh * __builtin_amdgcn_rcpf(1.0f + eh);  // eh<=1: safe
  float g = (hid >= 0.0f) ? (hid + 0.5f) : gneg;
  v = z * g;
}

// ---------- fused GEMM + gate epilogue + chunk-local scan (pass1) ----------
// (R1 structure, measured 92-93us.) Block covers 128 consecutive rows
// (= 4 chunks of 32 t's within one batch b) x 64 output channels [d0,d0+64).
// W-row permutation pairs hid/gate per lane. Epilogue: (coef,v)->half2 into
// a 32 KB LDS transpose (reusing the staging LDS), then (1) coalesced uint4
// row-writes of cv, (2) per-thread 32-step scan giving chunk coeff-product P
// and local h.
__global__ __launch_bounds__(256) void gemm_fused(const us* __restrict__ A,
                                                  const us* __restrict__ B,
                                                  unsigned* __restrict__ cv,
                                                  float* __restrict__ cp,
                                                  float* __restrict__ ch) {
  __shared__ __align__(16) us smem[BM * BK + BN * BK];  // 32 KB
  us* As = smem;
  us* Bs = smem + BM * BK;
  unsigned* T = (unsigned*)smem;    // epilogue reuse: [128 rows][64 d] uint

  const int tid  = threadIdx.x;
  const int lane = tid & 63;
  const int w    = tid >> 6;      // wave 0..3
  const int wm   = w & 1;         // 2x2 wave grid
  const int wn   = w >> 1;
  const long bm  = (long)blockIdx.x * BM;
  const int  d0  = blockIdx.y * 64;

  // staging: each global_load_lds covers 8 rows x 64 cols (1 KiB)
  const int srow = lane >> 3;                 // row within 8-row group
  const int sseg = (lane & 7) ^ srow;         // XOR-permuted source segment

  const int fr = lane & 15;
  const int fq = lane >> 4;                   // 0..3

  int aoff[4][2], boff[4][2];
#pragma unroll
  for (int mt = 0; mt < 4; ++mt) {
    int row = wm * 64 + mt * 16 + fr;
#pragma unroll
    for (int kk = 0; kk < 2; ++kk) {
      int seg = kk * 4 + fq;
      aoff[mt][kk] = row * BK + ((seg ^ (row & 7)) * 8);
    }
  }
#pragma unroll
  for (int nt = 0; nt < 4; ++nt) {
    int row = wn * 64 + nt * 16 + fr;
#pragma unroll
    for (int kk = 0; kk < 2; ++kk) {
      int seg = kk * 4 + fq;
      boff[nt][kk] = row * BK + ((seg ^ (row & 7)) * 8);
    }
  }

  f4v acc[4][4] = {};

  const us* Ap[4];
  const us* Bp[4];
#pragma unroll
  for (int i = 0; i < 4; ++i) {
    int lr = w * 32 + i * 8 + srow;           // local tile row
    Ap[i] = A + (bm + lr) * (long)KK + sseg * 8;
    int wrow = d0 + ((lr >> 5) << 4) + (lr & 15) + (((lr >> 4) & 1) << 10);
    Bp[i] = B + (long)wrow * KK + sseg * 8;
  }

  for (int kt = 0; kt < KK / BK; ++kt) {
    __syncthreads();   // previous tile's reads done before overwrite
#pragma unroll
    for (int i = 0; i < 4; ++i) {
      GLD16(Ap[i], &As[(w * 32 + i * 8) * BK]);
      GLD16(Bp[i], &Bs[(w * 32 + i * 8) * BK]);
      Ap[i] += BK;
      Bp[i] += BK;
    }
    __syncthreads();   // staging visible

#pragma unroll
    for (int kk = 0; kk < 2; ++kk) {
      s8v af[4], bf[4];
#pragma unroll
      for (int mt = 0; mt < 4; ++mt) af[mt] = *(const s8v*)&As[aoff[mt][kk]];
#pragma unroll
      for (int nt = 0; nt < 4; ++nt) bf[nt] = *(const s8v*)&Bs[boff[nt][kk]];
#pragma unroll
      for (int mt = 0; mt < 4; ++mt)
#pragma unroll
        for (int nt = 0; nt < 4; ++nt)
          acc[mt][nt] = __builtin_amdgcn_mfma_f32_16x16x32_bf16(
              af[mt], bf[nt], acc[mt][nt], 0, 0, 0);
    }
  }

  // ---- epilogue ----
  __syncthreads();   // all waves done with As/Bs; reuse LDS as T
  // C/D row = fq*4 + r, col = fr (m89 layout); hid/gate pair = (nt=2p, 2p+1)
#pragma unroll
  for (int mt = 0; mt < 4; ++mt) {
    int lr0 = wm * 64 + mt * 16 + fq * 4;     // local row base
#pragma unroll
    for (int p = 0; p < 2; ++p) {
      int ld = (wn * 2 + p) * 16 + fr;        // local d
      f4v hv = acc[mt][2 * p];
      f4v gv = acc[mt][2 * p + 1];
#pragma unroll
      for (int r = 0; r < 4; ++r) {
        float coef, v;
        gate_cv(hv[r], gv[r], coef, v);
        pk2 pk = __builtin_amdgcn_cvt_pkrtz(coef, v);   // (lo=coef, hi=v)
        T[(lr0 + r) * 64 + ld] = __builtin_bit_cast(unsigned, pk);
      }
    }
  }
  __syncthreads();   // transpose complete

  // (1) coalesced cv writes: 2048 uint4 chunks (128 rows x 16), 8 per thread
#pragma unroll
  for (int j = 0; j < 8; ++j) {
    int chunk = j * 256 + tid;
    int row = chunk >> 4;                     // 0..127
    int q   = chunk & 15;                     // 16B chunk within row
    uint4 val = *(const uint4*)&T[row * 64 + q * 4];
    *(uint4*)(cv + (size_t)(bm + row) * DD + d0 + q * 4) = val;
  }

  // (2) chunk-local scan: thread -> (local chunk c = tid>>6, d = tid&63)
  {
    const int d = tid & 63;
    const int c = tid >> 6;                   // 0..3
    float P = 1.0f, h = 0.0f;
#pragma unroll
    for (int i = 0; i < CHUNK; ++i) {
      unsigned u = T[(c * CHUNK + i) * 64 + d];
      __half2 hv = *(__half2*)&u;
      float cf = __half2float(hv.x);
      h = fmaf(cf, h, __half2float(hv.y));
      P *= cf;
    }
    const int b  = (int)(bm / SS);
    const int cg = (int)((bm % SS) / CHUNK) + c;   // global chunk 0..127
    const int idx = cg * BDD + b * DD + d0 + d;    // [chunk][b][d]
    cp[idx] = P;
    ch[idx] = h;
  }
}

// pass2: serial scan over NC chunk summaries per sequence; 4096 threads.
// (R1 version, measured-best: 16-deep load batching for ILP; the R2
// lookback fusion regressed +7us and was reverted.)
__global__ __launch_bounds__(256) void scan_pass2(const float* __restrict__ cp,
                                                  const float* __restrict__ ch,
                                                  float* __restrict__ carry) {
  const int bd = blockIdx.x * 256 + threadIdx.x;  // 0..4095
  float h = 0.0f;
  for (int cb = 0; cb < NC; cb += 16) {
    float p[16], v[16];
#pragma unroll
    for (int i = 0; i < 16; ++i) {
      p[i] = cp[(cb + i) * BDD + bd];
      v[i] = ch[(cb + i) * BDD + bd];
    }
#pragma unroll
    for (int i = 0; i < 16; ++i) {
      carry[(cb + i) * BDD + bd] = h;               // carry INTO chunk cb+i
      h = fmaf(p[i], h, v[i]);
    }
  }
}

// pass3: re-run each chunk with the correct carry-in, write out.
// R5: 8-deep load batching (loads are independent of the h chain; fma order
// per channel unchanged -> bit-identical out). 16B/lane uint4 cv read,
// float4 out write; 4 channels/thread; per t the block streams one 4 KiB cv
// row and one 4 KiB out row, fully coalesced.
__global__ __launch_bounds__(256) void scan_pass3(const uint4* __restrict__ cv,
                                                  const float* __restrict__ carry,
                                                  float4* __restrict__ out) {
  const int q = threadIdx.x;                      // 0..255 channel-quad
  const int c = blockIdx.y;
  const int b = blockIdx.z;
  const size_t rbase = ((size_t)b * SS + (size_t)c * CHUNK) * DQ + q;
  const uint4* base = cv + rbase;
  float4* obase = out + rbase;
  float4 h = *(const float4*)&carry[c * BDD + b * DD + 4 * q];
  for (int tb = 0; tb < CHUNK; tb += 8) {
    uint4 u[8];
#pragma unroll
    for (int j = 0; j < 8; ++j) u[j] = base[(size_t)(tb + j) * DQ];
#pragma unroll
    for (int j = 0; j < 8; ++j) {
      __half2 a0 = *(__half2*)&u[j].x;
      __half2 a1 = *(__half2*)&u[j].y;
      __half2 a2 = *(__half2*)&u[j].z;
      __half2 a3 = *(__half2*)&u[j].w;
      h.x = fmaf(__half2float(a0.x), h.x, __half2float(a0.y));
      h.y = fmaf(__half2float(a1.x), h.y, __half2float(a1.y));
      h.z = fmaf(__half2float(a2.x), h.z, __half2float(a2.y));
      h.w = fmaf(__half2float(a3.x), h.w, __half2float(a3.y));
      obase[(size_t)(tb + j) * DQ] = h;
    }
  }
}

// ---------- launch ----------
extern "C" void kernel_launch(void* const* d_in, const int* in_sizes, int n_in,
                              void* d_out, int out_size, void* d_ws, size_t ws_size,
                              hipStream_t stream) {
  const float* x = (const float*)d_in[0];   // [4,4096,1024] fp32
  const float* W = (const float*)d_in[1];   // [2048,1024]  fp32
  float4* out = (float4*)d_out;             // [4,4096,1024] fp32

  const long nx = (long)MM * KK;            // 16,777,216
  const long nw = (long)NN * KK;            //  2,097,152

  // workspace layout (~106 MiB total)
  char* ws = (char*)d_ws;
  unsigned* cv = (unsigned*)ws;      ws += (size_t)MM * DD * sizeof(unsigned); // 64 MiB
  us* xb = (us*)ws;                  ws += (size_t)nx * sizeof(us);            // 32 MiB
  us* wb = (us*)ws;                  ws += (size_t)nw * sizeof(us);            //  4 MiB
  float* cp = (float*)ws;            ws += (size_t)NC * BDD * sizeof(float);   //  2 MiB
  float* chh = (float*)ws;           ws += (size_t)NC * BDD * sizeof(float);   //  2 MiB
  float* carry = (float*)ws;         ws += (size_t)NC * BDD * sizeof(float);   //  2 MiB

  cvt_both<<<(int)((nx + nw) / 4 / 256), 256, 0, stream>>>(x, W, xb, wb, nx);

  gemm_fused<<<dim3(MM / BM, DD / 64), 256, 0, stream>>>(xb, wb, cv, cp, chh);

  scan_pass2<<<dim3(BDD / 256), 256, 0, stream>>>(cp, chh, carry);
  scan_pass3<<<dim3(1, NC, BB), 256, 0, stream>>>((const uint4*)cv, carry, out);
}